// Round 6
// baseline (305.705 us; speedup 1.0000x reference)
//
#include <hip/hip_runtime.h>
#include <math.h>

#define B     32
#define CIN   128
#define NN    8192
#define N1    8190     // output length after k=3 valid conv
#define CH    10
#define TOUT  252      // diag outputs per block (h2 tile = TOUT+4 = 256 cols)
#define NTILE 33       // ceil(8190/252)
#define COLS  264      // staged cols per channel: [t0-4, t0+259], 66 float4
#define CPC   8        // channels per chunk
#define NCHK  16       // chunks

// K0: transpose w1[o][ci][k] -> wT[ci][o*3+k] (rows padded to 32 floats)
// so k_main's per-channel 30 weights are contiguous wave-uniform s_loads.
__global__ void k0_prep(const float* __restrict__ w1, float* __restrict__ wT)
{
    const int i = blockIdx.x * 256 + threadIdx.x;     // 0..4095
    if (i < CIN * 32) {
        const int ci = i >> 5, r = i & 31;
        float v = 0.f;
        if (r < 30) {
            const int o = r / 3, k = r - o * 3;
            v = w1[(o * CIN + ci) * 3 + k];
        }
        wT[i] = v;
    }
}

typedef __attribute__((address_space(1))) void g_void;
typedef __attribute__((address_space(3))) void l_void;

__device__ __forceinline__ void gld16(const float* g, float* l)
{
    // async global->LDS, 16B per lane; LDS dest = wave-uniform base + lane*16
    __builtin_amdgcn_global_load_lds((g_void*)g, (l_void*)l, 16, 0, 0);
}

// Counted waits / raw barriers (T4): NEVER drain vmcnt to 0 mid-loop.
// vmcnt retires IN ISSUE ORDER. R4/R5's identical-absmax failure: the 3
// prologue stage3 calls had no fences between them, so LLVM interleaved the
// 9 non-aliasing LDS-DMA writes -> "oldest 3 = chunk 0" broke. In-loop the
// asm volatile "memory" ops serialize every stage3 against the next, so
// counting is sound there; the prologue now ends in a FULL drain instead.
#define WAITVM(N) asm volatile("s_waitcnt vmcnt(" #N ")" ::: "memory")
#define BARRIER() asm volatile("s_barrier" ::: "memory")
// Post-read barrier: this wave's ds_reads retired before anyone refills.
#define BAR_RD()  asm volatile("s_waitcnt lgkmcnt(0)\n\ts_barrier" ::: "memory")

// Stage one f4 of chunk: f4 index i -> buf bytes [16i,16i+16).
__device__ __forceinline__ void stage_one(const float* __restrict__ rowbase,
                                          float* buf, int i, int scol0)
{
    const int row = (int)((unsigned)i / 66u);
    int col = scol0 + (i - row * 66) * 4;
    col = col < 0 ? 0 : (col > NN - 4 ? NN - 4 : col);
    gld16(rowbase + (size_t)row * NN + col, buf + (size_t)i * 4);
}

// Stage chunk c (8 ch x 264 cols = 528 f4). UNIFORM COUNT: every wave issues
// exactly 3 gld16 (132 f4/wave = 64 + 64 + 4-lane tail) so literal vmcnt(N)
// counting is identical across waves.
__device__ __forceinline__ void stage3(const float* __restrict__ sigb, int c,
                                       float* buf, int wav, int lane, int scol0)
{
    const float* rowbase = sigb + (size_t)(c * CPC) * NN;
    const int base = wav * 132;
    stage_one(rowbase, buf, base + lane, scol0);
    stage_one(rowbase, buf, base + 64 + lane, scol0);
    if (lane < 4)
        stage_one(rowbase, buf, base + 128 + lane, scol0);
}

// FMA over one staged chunk. LDS float idx tid+2 <=> col g = t0-2+tid.
__device__ __forceinline__ void chunkfma(const float* __restrict__ cur, int c,
                                         int tid, float (&y)[CH],
                                         const float* __restrict__ wT)
{
    const float* bl = cur + tid + 2;
#pragma unroll
    for (int j = 0; j < CPC; ++j) {
        const float s0 = bl[j * COLS + 0];
        const float s1 = bl[j * COLS + 1];
        const float s2 = bl[j * COLS + 2];
        const float* wrow = wT + (c * CPC + j) * 32;  // uniform -> s_loads
#pragma unroll
        for (int o = 0; o < CH; ++o) {
            y[o] = fmaf(wrow[o * 3 + 0], s0, y[o]);
            y[o] = fmaf(wrow[o * 3 + 1], s1, y[o]);
            y[o] = fmaf(wrow[o * 3 + 2], s2, y[o]);
        }
    }
}

// K_MAIN: whole pipeline per 252-output tile, 256 threads.
// Phase 1: conv1 with TRIPLE-buffered global_load_lds staging. Prologue
//   stages chunks 0-2 then does ONE full drain (__syncthreads) — no
//   reliance on prologue issue order. Steady loop uses counted vmcnt(6)
//   + raw barriers: chunks stay in flight ACROSS barriers (T3/T4); the
//   refills are serialized by the asm barriers so in-order counting holds.
//   Per-iter: [vmcnt(6); bar; fma c; lgkm(0)+bar; stage c+3].
// Phase 2 (LDS): convT(k=3)+relu+1x1+sigmoid -> lr; tridiag+log; block sum.
__global__ __launch_bounds__(256, 4) void k_main(
    const float* __restrict__ sig, const float* __restrict__ wT,
    const float* __restrict__ b1, const float* __restrict__ w2, const float* __restrict__ b2,
    const float* __restrict__ wt, const float* __restrict__ bt,
    const float* __restrict__ w3, const float* __restrict__ b3,
    const float* __restrict__ cd, const float* __restrict__ cstp,
    float* __restrict__ outv, float* __restrict__ bsums)
{
    __shared__ float bufA[CPC * COLS];   // 8448 B
    __shared__ float bufB[CPC * COLS];   // 8448 B
    __shared__ float bufC[CPC * COLS];   // 8448 B
    __shared__ float h2s[CH * 256];      // 10240 B  [o][col]
    __shared__ float lsh[256], rsh[256];
    __shared__ float red[4];

    const int tid  = threadIdx.x;
    const int wav  = tid >> 6;
    const int lane = tid & 63;
    const int b    = blockIdx.y;
    const int t0   = blockIdx.x * TOUT;
    const int scol0 = t0 - 4;                         // 16B-aligned (252bx%4==0)
    const int g    = t0 - 2 + tid;                    // h2 column of this thread
    const bool gvalid = (g >= 0) && (g < N1);
    const float* __restrict__ sigb = sig + (size_t)b * CIN * NN;

    float y[CH];
#pragma unroll
    for (int o = 0; o < CH; ++o) y[o] = b1[o];

    // ---- Phase 1 prologue: stage chunks 0-2, then ONE full drain ----
    stage3(sigb, 0, bufA, wav, lane, scol0);
    __builtin_amdgcn_sched_barrier(0);
    stage3(sigb, 1, bufB, wav, lane, scol0);
    __builtin_amdgcn_sched_barrier(0);
    stage3(sigb, 2, bufC, wav, lane, scol0);
    __syncthreads();                                  // vmcnt(0): chunks 0-2 in LDS

    float* p0 = bufA; float* p1 = bufB; float* p2 = bufC;
    for (int c = 0; c < 13; ++c) {
        WAITVM(6);                                    // no-op c<3; then: chunk c landed
        BARRIER();                                    // all waves' chunk-c loads visible
        chunkfma(p0, c, tid, y, wT);
        BAR_RD();                                     // reads RETIRED, then barrier
        stage3(sigb, c + 3, p0, wav, lane, scol0);    // refill freed buffer
        float* t = p0; p0 = p1; p1 = p2; p2 = t;
    }
    // epilogue: chunks 13,14,15 — outstanding 9 here; waits 6,3,0; no refills.
    WAITVM(6); BARRIER(); chunkfma(p0, 13, tid, y, wT);
    { float* t = p0; p0 = p1; p1 = p2; p2 = t; }
    WAITVM(3); BARRIER(); chunkfma(p0, 14, tid, y, wT);
    { float* t = p0; p0 = p1; p1 = p2; p2 = t; }
    WAITVM(0); BARRIER(); chunkfma(p0, 15, tid, y, wT);

    // conv2 (1x1) + relu -> LDS (zero outside [0,N1) for convT zero-padding)
#pragma unroll
    for (int o = 0; o < CH; ++o) y[o] = fmaxf(y[o], 0.f);
#pragma unroll
    for (int o = 0; o < CH; ++o) {
        float a = b2[o];
#pragma unroll
        for (int i = 0; i < CH; ++i) a = fmaf(w2[o * CH + i], y[i], a);
        h2s[o * 256 + tid] = gvalid ? fmaxf(a, 0.f) : 0.f;
    }
    __syncthreads();

    // convT + relu + 1x1 + sigmoid -> lr at s = t0 + tid (tid < 254)
    const int s = t0 + tid;
    if (tid < 254 && s < NN) {
        float acc[CH];
#pragma unroll
        for (int o = 0; o < CH; ++o) acc[o] = bt[o];
#pragma unroll
        for (int i = 0; i < CH; ++i) {
            const float a0 = h2s[i * 256 + tid];      // h2[s-2]
            const float a1 = h2s[i * 256 + tid + 1];  // h2[s-1]
            const float a2 = h2s[i * 256 + tid + 2];  // h2[s]
            const float* wp = wt + i * CH * 3;        // contiguous uniform
#pragma unroll
            for (int o = 0; o < CH; ++o) {
                acc[o] = fmaf(wp[o * 3 + 0], a2, acc[o]);
                acc[o] = fmaf(wp[o * 3 + 1], a1, acc[o]);
                acc[o] = fmaf(wp[o * 3 + 2], a0, acc[o]);
            }
        }
        float l = b3[0], r = b3[1];
#pragma unroll
        for (int o = 0; o < CH; ++o) {
            const float h3 = fmaxf(acc[o], 0.f);
            l = fmaf(w3[o],      h3, l);
            r = fmaf(w3[CH + o], h3, r);
        }
        lsh[tid] = 1.f / (1.f + __expf(-l));
        rsh[tid] = 1.f / (1.f + __expf(-r));
    }
    __syncthreads();

    // tridiagonal update + log for t = t0 + tid (tid < TOUT)
    float vlog = 0.f;
    const int t = t0 + tid;
    if (tid < TOUT && t < N1) {
        const float c0 = cd[(size_t)b * (NN - 1) + t];
        const float c1 = cd[(size_t)b * (NN - 1) + t + 1];
        const float mi = c1 * rsh[tid + 1] + c0 * lsh[tid + 1];
        const float mo = rsh[tid] + lsh[tid + 2];
        vlog = __logf(cstp[0] * mi / mo);
        outv[(size_t)b * N1 + t] = vlog;
    }

    // block sum: wave shuffle reduce, then 4 partials through LDS
    float vs = vlog;
#pragma unroll
    for (int off = 32; off > 0; off >>= 1) vs += __shfl_down(vs, off);
    if ((tid & 63) == 0) red[tid >> 6] = vs;
    __syncthreads();
    if (tid == 0)
        bsums[blockIdx.y * NTILE + blockIdx.x] = red[0] + red[1] + red[2] + red[3];
}

// K3: every block redundantly reduces the 1056 bsums (L2-hot), subtracts mean.
__global__ __launch_bounds__(256) void k3_meansub(
    const float* __restrict__ bsums, float* __restrict__ outv, int n)
{
    __shared__ float red[256];
    const int tid = threadIdx.x;
    float s = 0.f;
    for (int i = tid; i < NTILE * B; i += 256) s += bsums[i];
    red[tid] = s;
    __syncthreads();
#pragma unroll
    for (int st = 128; st > 0; st >>= 1) {
        if (tid < st) red[tid] += red[tid + st];
        __syncthreads();
    }
    const float mean = red[0] / (float)(B * N1);
    __syncthreads();
    const int i = blockIdx.x * 256 + tid;
    if (i < n) outv[i] -= mean;
}

extern "C" void kernel_launch(void* const* d_in, const int* in_sizes, int n_in,
                              void* d_out, int out_size, void* d_ws, size_t ws_size,
                              hipStream_t stream)
{
    const float* sig = (const float*)d_in[0];
    const float* cd  = (const float*)d_in[1];
    // d_in[2] = index_diag (1 for these shapes)
    const float* w1  = (const float*)d_in[3];
    const float* b1  = (const float*)d_in[4];
    const float* w2  = (const float*)d_in[5];
    const float* b2  = (const float*)d_in[6];
    const float* wt  = (const float*)d_in[7];
    const float* bt  = (const float*)d_in[8];
    const float* w3  = (const float*)d_in[9];
    const float* b3  = (const float*)d_in[10];
    const float* cst = (const float*)d_in[11];

    float* outv = (float*)d_out;

    // workspace layout (floats)
    float* ws   = (float*)d_ws;
    float* wT   = ws;                  // CIN*32 = 4096
    float* bsum = wT + CIN * 32;       // NTILE*B = 1056

    k0_prep   <<<dim3(16), dim3(256), 0, stream>>>(w1, wT);
    k_main    <<<dim3(NTILE, B), dim3(256), 0, stream>>>(sig, wT, b1, w2, b2,
                                                         wt, bt, w3, b3, cd, cst, outv, bsum);
    k3_meansub<<<dim3((out_size + 255) / 256), dim3(256), 0, stream>>>(bsum, outv, out_size);
}

// Round 7
// 242.573 us; speedup vs baseline: 1.2603x; 1.2603x over previous
//
#include <hip/hip_runtime.h>
#include <math.h>

#define B     32
#define CIN   128
#define NN    8192
#define N1    8190     // output length after k=3 valid conv
#define CH    10
#define TPB   64       // ONE wave per block: barriers are wave-local, blocks
                       // on a CU run phase-UNcorrelated (m114 overlap)
#define TOUT  60       // diag outputs per block
#define NTILE 137      // ceil(8190/60)
#define COLS  68       // staged cols per channel: [t0-4, t0+63], 17 float4
#define F4PC  17       // float4 per channel row
#define CPC   8        // channels per chunk
#define NCHK  16       // chunks

// K0: transpose w1[o][ci][k] -> wT[ci][o*3+k] (rows padded to 32 floats)
// so k_main's per-channel 30 weights are contiguous wave-uniform s_loads.
__global__ void k0_prep(const float* __restrict__ w1, float* __restrict__ wT)
{
    const int i = blockIdx.x * 256 + threadIdx.x;     // 0..4095
    if (i < CIN * 32) {
        const int ci = i >> 5, r = i & 31;
        float v = 0.f;
        if (r < 30) {
            const int o = r / 3, k = r - o * 3;
            v = w1[(o * CIN + ci) * 3 + k];
        }
        wT[i] = v;
    }
}

typedef __attribute__((address_space(1))) void g_void;
typedef __attribute__((address_space(3))) void l_void;

__device__ __forceinline__ void gld16(const float* g, float* l)
{
    // async global->LDS, 16B per lane; LDS dest = wave-uniform base + lane*16
    __builtin_amdgcn_global_load_lds((g_void*)g, (l_void*)l, 16, 0, 0);
}

// Stage one f4: f4 index i -> buf bytes [16i,16i+16).
// Per-lane i = uniform base + lane, so dest = uniform + lane*16 (HW pattern).
__device__ __forceinline__ void stage_one(const float* __restrict__ rowbase,
                                          float* buf, int i, int scol0)
{
    const int row = (int)((unsigned)i / (unsigned)F4PC);
    int col = scol0 + (i - row * F4PC) * 4;
    col = col < 0 ? 0 : (col > NN - 4 ? NN - 4 : col);  // clamped slots are
    gld16(rowbase + (size_t)row * NN + col, buf + (size_t)i * 4); // gvalid-masked
}

// Stage chunk c: 8 ch x 17 f4 = 136 f4, one wave: 64 + 64 + 8-lane tail.
__device__ __forceinline__ void stage_chunk(const float* __restrict__ sigb, int c,
                                            float* buf, int tid, int scol0)
{
    const float* rowbase = sigb + (size_t)(c * CPC) * NN;
    stage_one(rowbase, buf, tid, scol0);
    stage_one(rowbase, buf, 64 + tid, scol0);
    if (tid < 8)
        stage_one(rowbase, buf, 128 + tid, scol0);
}

// FMA over one staged chunk. LDS float idx tid+2 <=> col g = t0-2+tid.
__device__ __forceinline__ void chunkfma(const float* __restrict__ cur, int c,
                                         int tid, float (&y)[CH],
                                         const float* __restrict__ wT)
{
    const float* bl = cur + tid + 2;
#pragma unroll
    for (int j = 0; j < CPC; ++j) {
        const float s0 = bl[j * COLS + 0];
        const float s1 = bl[j * COLS + 1];
        const float s2 = bl[j * COLS + 2];
        const float* wrow = wT + (c * CPC + j) * 32;  // uniform -> s_loads
#pragma unroll
        for (int o = 0; o < CH; ++o) {
            y[o] = fmaf(wrow[o * 3 + 0], s0, y[o]);
            y[o] = fmaf(wrow[o * 3 + 1], s1, y[o]);
            y[o] = fmaf(wrow[o * 3 + 2], s2, y[o]);
        }
    }
}

// K_MAIN: whole pipeline per 60-output tile, ONE WAVE per block.
// R3's structure (double-buffered global_load_lds + __syncthreads) was best
// (77us); its stall was PHASE-LOCKING: 4-5 resident 4-wave blocks launched
// in sync hit their vmcnt(0) drains simultaneously -> CU 75% idle
// (VALUBusy 25%). R4-R6 counted-vmcnt variants regressed (142us) or raced.
// Fix: 1-wave blocks. The drain stalls only this wave; ~16 independent
// blocks/CU in uncorrelated phases cover each other's latency (m114).
__global__ __launch_bounds__(TPB) void k_main(
    const float* __restrict__ sig, const float* __restrict__ wT,
    const float* __restrict__ b1, const float* __restrict__ w2, const float* __restrict__ b2,
    const float* __restrict__ wt, const float* __restrict__ bt,
    const float* __restrict__ w3, const float* __restrict__ b3,
    const float* __restrict__ cd, const float* __restrict__ cstp,
    float* __restrict__ outv, float* __restrict__ bsums)
{
    __shared__ float bufA[CPC * COLS];   // 2176 B
    __shared__ float bufB[CPC * COLS];   // 2176 B
    __shared__ float h2s[CH * TPB];      // 2560 B  [o][col]
    __shared__ float lsh[TPB], rsh[TPB];

    const int tid = threadIdx.x;
    const int b   = blockIdx.y;
    const int t0  = blockIdx.x * TOUT;
    const int scol0 = t0 - 4;                         // 4-col aligned (60bx%4==0)
    const int g   = t0 - 2 + tid;                     // h2 column of this thread
    const bool gvalid = (g >= 0) && (g < N1);
    const float* __restrict__ sigb = sig + (size_t)b * CIN * NN;

    float y[CH];
#pragma unroll
    for (int o = 0; o < CH; ++o) y[o] = b1[o];

    // ---- Phase 1: 16 chunks x 8 channels, double-buffered LDS staging ----
    stage_chunk(sigb, 0, bufA, tid, scol0);
    __syncthreads();                                  // wave-local drain

    for (int c = 0; c < NCHK; ++c) {
        float* cur = (c & 1) ? bufB : bufA;
        float* nxt = (c & 1) ? bufA : bufB;
        if (c < NCHK - 1) stage_chunk(sigb, c + 1, nxt, tid, scol0);
        chunkfma(cur, c, tid, y, wT);
        __syncthreads();                              // reads done + prefetch drained
    }

    // conv2 (1x1) + relu -> LDS (zero outside [0,N1) for convT zero-padding)
#pragma unroll
    for (int o = 0; o < CH; ++o) y[o] = fmaxf(y[o], 0.f);
#pragma unroll
    for (int o = 0; o < CH; ++o) {
        float a = b2[o];
#pragma unroll
        for (int i = 0; i < CH; ++i) a = fmaf(w2[o * CH + i], y[i], a);
        h2s[o * TPB + tid] = gvalid ? fmaxf(a, 0.f) : 0.f;
    }
    __syncthreads();

    // convT + relu + 1x1 + sigmoid -> lr at s = t0 + tid (tid < 62)
    const int s = t0 + tid;
    if (tid < TOUT + 2 && s < NN) {
        float acc[CH];
#pragma unroll
        for (int o = 0; o < CH; ++o) acc[o] = bt[o];
#pragma unroll
        for (int i = 0; i < CH; ++i) {
            const float a0 = h2s[i * TPB + tid];      // h2[s-2]
            const float a1 = h2s[i * TPB + tid + 1];  // h2[s-1]
            const float a2 = h2s[i * TPB + tid + 2];  // h2[s]
            const float* wp = wt + i * CH * 3;        // contiguous uniform
#pragma unroll
            for (int o = 0; o < CH; ++o) {
                acc[o] = fmaf(wp[o * 3 + 0], a2, acc[o]);
                acc[o] = fmaf(wp[o * 3 + 1], a1, acc[o]);
                acc[o] = fmaf(wp[o * 3 + 2], a0, acc[o]);
            }
        }
        float l = b3[0], r = b3[1];
#pragma unroll
        for (int o = 0; o < CH; ++o) {
            const float h3 = fmaxf(acc[o], 0.f);
            l = fmaf(w3[o],      h3, l);
            r = fmaf(w3[CH + o], h3, r);
        }
        lsh[tid] = 1.f / (1.f + __expf(-l));
        rsh[tid] = 1.f / (1.f + __expf(-r));
    }
    __syncthreads();

    // tridiagonal update + log for t = t0 + tid (tid < TOUT)
    float vlog = 0.f;
    const int t = t0 + tid;
    if (tid < TOUT && t < N1) {
        const float c0 = cd[(size_t)b * (NN - 1) + t];
        const float c1 = cd[(size_t)b * (NN - 1) + t + 1];
        const float mi = c1 * rsh[tid + 1] + c0 * lsh[tid + 1];
        const float mo = rsh[tid] + lsh[tid + 2];
        vlog = __logf(cstp[0] * mi / mo);
        outv[(size_t)b * N1 + t] = vlog;
    }

    // block sum: single-wave shuffle reduce
    float vs = vlog;
#pragma unroll
    for (int off = 32; off > 0; off >>= 1) vs += __shfl_down(vs, off);
    if (tid == 0)
        bsums[blockIdx.y * NTILE + blockIdx.x] = vs;
}

// K3: every block redundantly reduces the 4384 bsums (L2-hot), subtracts mean.
__global__ __launch_bounds__(256) void k3_meansub(
    const float* __restrict__ bsums, float* __restrict__ outv, int n)
{
    __shared__ float red[256];
    const int tid = threadIdx.x;
    float s = 0.f;
    for (int i = tid; i < NTILE * B; i += 256) s += bsums[i];
    red[tid] = s;
    __syncthreads();
#pragma unroll
    for (int st = 128; st > 0; st >>= 1) {
        if (tid < st) red[tid] += red[tid + st];
        __syncthreads();
    }
    const float mean = red[0] / (float)(B * N1);
    __syncthreads();
    const int i = blockIdx.x * 256 + tid;
    if (i < n) outv[i] -= mean;
}

extern "C" void kernel_launch(void* const* d_in, const int* in_sizes, int n_in,
                              void* d_out, int out_size, void* d_ws, size_t ws_size,
                              hipStream_t stream)
{
    const float* sig = (const float*)d_in[0];
    const float* cd  = (const float*)d_in[1];
    // d_in[2] = index_diag (1 for these shapes)
    const float* w1  = (const float*)d_in[3];
    const float* b1  = (const float*)d_in[4];
    const float* w2  = (const float*)d_in[5];
    const float* b2  = (const float*)d_in[6];
    const float* wt  = (const float*)d_in[7];
    const float* bt  = (const float*)d_in[8];
    const float* w3  = (const float*)d_in[9];
    const float* b3  = (const float*)d_in[10];
    const float* cst = (const float*)d_in[11];

    float* outv = (float*)d_out;

    // workspace layout (floats)
    float* ws   = (float*)d_ws;
    float* wT   = ws;                  // CIN*32 = 4096
    float* bsum = wT + CIN * 32;       // NTILE*B = 4384

    k0_prep   <<<dim3(16), dim3(256), 0, stream>>>(w1, wT);
    k_main    <<<dim3(NTILE, B), dim3(TPB), 0, stream>>>(sig, wT, b1, w2, b2,
                                                         wt, bt, w3, b3, cd, cst, outv, bsum);
    k3_meansub<<<dim3((out_size + 255) / 256), dim3(256), 0, stream>>>(bsum, outv, out_size);
}